// Round 1
// baseline (4855.264 us; speedup 1.0000x reference)
//
#include <hip/hip_runtime.h>
#include <math.h>

#define BB 128
#define TT 512
#define HH 128
#define G4 512      // 4*H
#define CC 128
#define WW 32
#define NB 2        // batches per block in K1

// ---- workspace layout (floats) ----
#define OFF_WT1   0
#define OFF_WTI2  (OFF_WT1  + G4*HH)        // 65536
#define OFF_WTH2  (OFF_WTI2 + G4*HH)
#define OFF_FCWT  (OFF_WTH2 + G4*HH)
#define OFF_B1    (OFF_FCWT + CC*HH)
#define OFF_B2    (OFF_B1 + G4)
#define OFF_H2A   (OFF_B2 + G4)             // [T][B][H], later y in-place
#define OFF_DOLD  (OFF_H2A + TT*BB*HH)
#define OFF_DH    (OFF_DOLD + TT*BB)
#define OFF_MT    (OFF_DH + TT*BB)
#define OFF_ST    (OFF_MT + TT)
#define WS_FLOATS (OFF_ST + TT)

__device__ __forceinline__ float sigm(float v) {
    return 1.f / (1.f + __expf(-v));
}
__device__ __forceinline__ float ftanh(float v) {
    // 1 - 2/(e^{2v}+1): exact limits at +/-inf, no NaN
    return 1.f - 2.f / (__expf(2.f * v) + 1.f);
}

// K0: transpose weights for coalesced K1 access, combine biases
__global__ __launch_bounds__(256) void k0_prep(
    const float* __restrict__ Whh1, const float* __restrict__ Wih2,
    const float* __restrict__ Whh2, const float* __restrict__ fcW,
    const float* __restrict__ bih1, const float* __restrict__ bhh1,
    const float* __restrict__ bih2, const float* __restrict__ bhh2,
    float* __restrict__ WT1, float* __restrict__ WTi2, float* __restrict__ WTh2,
    float* __restrict__ fcWT, float* __restrict__ b1, float* __restrict__ b2)
{
    int idx = blockIdx.x * blockDim.x + threadIdx.x;
    if (idx < G4 * HH) {
        int j = idx / HH, k = idx % HH;   // source [j][k]
        WT1 [k * G4 + j] = Whh1[idx];
        WTi2[k * G4 + j] = Wih2[idx];
        WTh2[k * G4 + j] = Whh2[idx];
    }
    if (idx < CC * HH) {
        int c = idx / HH, h = idx % HH;
        fcWT[h * CC + c] = fcW[idx];
    }
    if (idx < G4) {
        b1[idx] = bih1[idx] + bhh1[idx];
        b2[idx] = bih2[idx] + bhh2[idx];
    }
}

// K1: the sequential 2-layer LSTM recurrence. 64 blocks x 512 threads,
// each block owns NB=2 batches, loops all T steps, state in LDS,
// weights streamed from global (L2-resident after first step).
__global__ __launch_bounds__(512) void k1_lstm(
    const float* __restrict__ x, const float* __restrict__ wih1,
    const float* __restrict__ WT1, const float* __restrict__ WTi2,
    const float* __restrict__ WTh2, const float* __restrict__ b1g,
    const float* __restrict__ b2g, float* __restrict__ h2a)
{
    __shared__ float s_h1[NB][HH], s_c1[NB][HH], s_h2[NB][HH], s_c2[NB][HH];
    __shared__ float s_g[NB][G4];
    __shared__ float s_b1[G4], s_b2[G4], s_wi1[G4];

    const int tid = threadIdx.x;
    const int b0 = blockIdx.x * NB;

    s_b1[tid]  = b1g[tid];
    s_b2[tid]  = b2g[tid];
    s_wi1[tid] = wih1[tid];
    if (tid < NB * HH) {
        int b = tid >> 7, k = tid & 127;
        s_h1[b][k] = 0.f; s_c1[b][k] = 0.f; s_h2[b][k] = 0.f; s_c2[b][k] = 0.f;
    }
    __syncthreads();

    for (int t = 0; t < TT; ++t) {
        const float x0 = x[(b0 + 0) * TT + t];
        const float x1 = x[(b0 + 1) * TT + t];

        // ---- layer 1 gates: gates1[b][j] = x_b*wih1[j] + b1[j] + sum_k h1[b][k]*Whh1[j][k]
        {
            float a0 = 0.f, a1 = 0.f;
            const float*  wp  = WT1 + tid;
            const float4* h10 = (const float4*)&s_h1[0][0];
            const float4* h11 = (const float4*)&s_h1[1][0];
            #pragma unroll 8
            for (int kq = 0; kq < HH / 4; ++kq) {
                float4 v0 = h10[kq];
                float4 v1 = h11[kq];
                float w0 = wp[(4*kq+0)*G4];
                float w1 = wp[(4*kq+1)*G4];
                float w2 = wp[(4*kq+2)*G4];
                float w3 = wp[(4*kq+3)*G4];
                a0 = fmaf(v0.x, w0, a0); a1 = fmaf(v1.x, w0, a1);
                a0 = fmaf(v0.y, w1, a0); a1 = fmaf(v1.y, w1, a1);
                a0 = fmaf(v0.z, w2, a0); a1 = fmaf(v1.z, w2, a1);
                a0 = fmaf(v0.w, w3, a0); a1 = fmaf(v1.w, w3, a1);
            }
            const float wi = s_wi1[tid], bb = s_b1[tid];
            s_g[0][tid] = fmaf(x0, wi, bb) + a0;
            s_g[1][tid] = fmaf(x1, wi, bb) + a1;
        }
        __syncthreads();

        // ---- layer 1 cell update
        if (tid < NB * HH) {
            int b = tid >> 7, k = tid & 127;
            float gi = s_g[b][k], gf = s_g[b][HH + k];
            float gg = s_g[b][2*HH + k], go = s_g[b][3*HH + k];
            float cn = sigm(gf) * s_c1[b][k] + sigm(gi) * ftanh(gg);
            s_c1[b][k] = cn;
            s_h1[b][k] = sigm(go) * ftanh(cn);
        }
        __syncthreads();

        // ---- layer 2 gates: input is c1 (per reference), recurrent h2
        {
            float a0 = 0.f, a1 = 0.f;
            const float*  wi  = WTi2 + tid;
            const float*  wh  = WTh2 + tid;
            const float4* c10 = (const float4*)&s_c1[0][0];
            const float4* c11 = (const float4*)&s_c1[1][0];
            const float4* h20 = (const float4*)&s_h2[0][0];
            const float4* h21 = (const float4*)&s_h2[1][0];
            #pragma unroll 4
            for (int kq = 0; kq < HH / 4; ++kq) {
                float4 cv0 = c10[kq], cv1 = c11[kq];
                float4 hv0 = h20[kq], hv1 = h21[kq];
                float wi0 = wi[(4*kq+0)*G4], wi1 = wi[(4*kq+1)*G4];
                float wi2 = wi[(4*kq+2)*G4], wi3 = wi[(4*kq+3)*G4];
                float wh0 = wh[(4*kq+0)*G4], wh1 = wh[(4*kq+1)*G4];
                float wh2 = wh[(4*kq+2)*G4], wh3 = wh[(4*kq+3)*G4];
                a0 = fmaf(cv0.x, wi0, a0); a1 = fmaf(cv1.x, wi0, a1);
                a0 = fmaf(hv0.x, wh0, a0); a1 = fmaf(hv1.x, wh0, a1);
                a0 = fmaf(cv0.y, wi1, a0); a1 = fmaf(cv1.y, wi1, a1);
                a0 = fmaf(hv0.y, wh1, a0); a1 = fmaf(hv1.y, wh1, a1);
                a0 = fmaf(cv0.z, wi2, a0); a1 = fmaf(cv1.z, wi2, a1);
                a0 = fmaf(hv0.z, wh2, a0); a1 = fmaf(hv1.z, wh2, a1);
                a0 = fmaf(cv0.w, wi3, a0); a1 = fmaf(cv1.w, wi3, a1);
                a0 = fmaf(hv0.w, wh3, a0); a1 = fmaf(hv1.w, wh3, a1);
            }
            const float bb = s_b2[tid];
            s_g[0][tid] = a0 + bb;
            s_g[1][tid] = a1 + bb;
        }
        __syncthreads();

        // ---- layer 2 cell update + h2 store
        if (tid < NB * HH) {
            int b = tid >> 7, k = tid & 127;
            float gi = s_g[b][k], gf = s_g[b][HH + k];
            float gg = s_g[b][2*HH + k], go = s_g[b][3*HH + k];
            float cn = sigm(gf) * s_c2[b][k] + sigm(gi) * ftanh(gg);
            s_c2[b][k] = cn;
            float hn = sigm(go) * ftanh(cn);
            s_h2[b][k] = hn;
            h2a[(size_t)t * (BB * HH) + (b0 + b) * HH + k] = hn;
        }
        __syncthreads();
    }
}

// K2: d_old[t,b] = h2[t,b,:].wt_old ; d_h[t,b] = h2[t,b,:].wt_h
__global__ __launch_bounds__(256) void k2_dots(
    const float* __restrict__ h2a, const float* __restrict__ w_t,
    float* __restrict__ dold, float* __restrict__ dh)
{
    const int lane = threadIdx.x & 63;
    const int wave = blockIdx.x * (blockDim.x >> 6) + (threadIdx.x >> 6);
    const int nw = gridDim.x * (blockDim.x >> 6);
    const float wh0 = w_t[lane],       wh1 = w_t[64 + lane];
    const float wo0 = w_t[128 + lane], wo1 = w_t[192 + lane];
    for (int row = wave; row < TT * BB; row += nw) {
        const float* p = h2a + (size_t)row * HH;
        float v0 = p[lane], v1 = p[64 + lane];
        float po = v0 * wo0 + v1 * wo1;
        float ph = v0 * wh0 + v1 * wh1;
        #pragma unroll
        for (int off = 32; off; off >>= 1) {
            po += __shfl_xor(po, off);
            ph += __shfl_xor(ph, off);
        }
        if (lane == 0) { dold[row] = po; dh[row] = ph; }
    }
}

// K3: per-t global softmax stats over valid (j,b): m[t], s[t]
__global__ __launch_bounds__(256) void k3_stats(
    const float* __restrict__ dold, const float* __restrict__ dh,
    float* __restrict__ mt, float* __restrict__ st)
{
    const int t = blockIdx.x;
    const int tid = threadIdx.x;
    const int cnt = (min(t, WW) + 1) * BB;      // valid entries
    const int jstart = max(t - (WW + 1), -1);   // j = jstart + (idx>>7)

    float m = -INFINITY;
    for (int idx = tid; idx < cnt; idx += 256) {
        int jj = idx >> 7, b = idx & 127;
        int j = jstart + jj;
        float sc = dh[t * BB + b] + (j >= 0 ? dold[j * BB + b] : 0.f);
        m = fmaxf(m, sc);
    }
    #pragma unroll
    for (int off = 32; off; off >>= 1) m = fmaxf(m, __shfl_xor(m, off));
    __shared__ float rbuf[4];
    int wv = tid >> 6, ln = tid & 63;
    if (ln == 0) rbuf[wv] = m;
    __syncthreads();
    m = fmaxf(fmaxf(rbuf[0], rbuf[1]), fmaxf(rbuf[2], rbuf[3]));

    float s = 0.f;
    for (int idx = tid; idx < cnt; idx += 256) {
        int jj = idx >> 7, b = idx & 127;
        int j = jstart + jj;
        float sc = dh[t * BB + b] + (j >= 0 ? dold[j * BB + b] : 0.f);
        s += __expf(sc - m);
    }
    #pragma unroll
    for (int off = 32; off; off >>= 1) s += __shfl_xor(s, off);
    __shared__ float sbuf[4];
    if (ln == 0) sbuf[wv] = s;
    __syncthreads();
    if (tid == 0) { mt[t] = m; st[t] = sbuf[0] + sbuf[1] + sbuf[2] + sbuf[3]; }
}

// K4: attention + y = h2 + attn, written IN-PLACE over h2a.
// One block per batch b; 33-slot LDS ring of h2 history.
__global__ __launch_bounds__(128) void k4_attn(
    float* __restrict__ h2a,
    const float* __restrict__ dold, const float* __restrict__ dh,
    const float* __restrict__ mt, const float* __restrict__ st)
{
    const int b = blockIdx.x;
    const int h = threadIdx.x;   // 0..127
    __shared__ float ring[33][HH];
    __shared__ float wj[33];

    #pragma unroll
    for (int s_ = 0; s_ < 33; ++s_) ring[s_][h] = 0.f;
    __syncthreads();

    for (int t = 0; t < TT; ++t) {
        float hv = h2a[(size_t)t * (BB * HH) + b * HH + h];
        if (h < 33) {
            int j = t - 33 + h;
            float w = 0.f;
            if (j >= 0)
                w = __expf(dold[j * BB + b] + dh[t * BB + b] - mt[t]) / st[t];
            wj[h] = w;
        }
        __syncthreads();   // wj ready (also guards ring write of prev iter)

        float acc = 0.f;
        const int r0 = t % 33;
        #pragma unroll
        for (int jj = 0; jj < 33; ++jj) {
            int r = r0 + jj; if (r >= 33) r -= 33;   // slot of h2[t-33+jj]
            acc = fmaf(wj[jj], ring[r][h], acc);
        }
        __syncthreads();   // all ring reads done before overwrite

        h2a[(size_t)t * (BB * HH) + b * HH + h] = hv + acc;  // y in-place
        ring[r0][h] = hv;                                    // push h2[t]
    }
}

// K5: out[b,t,c] = y[t,b,:].fcW[c,:] + fcb[c]
__global__ __launch_bounds__(256) void k5_fc(
    const float* __restrict__ y, const float* __restrict__ fcWT,
    const float* __restrict__ fcb, float* __restrict__ out)
{
    const int t  = blockIdx.x;
    const int b0 = blockIdx.y * 32;
    const int tid = threadIdx.x;
    __shared__ float ytile[32][HH];

    for (int i = tid; i < 32 * HH; i += 256) {
        int r = i >> 7, hh = i & 127;
        ytile[r][hh] = y[(size_t)t * (BB * HH) + (b0 + r) * HH + hh];
    }
    __syncthreads();

    const int c  = tid & 127;
    const int rh = tid >> 7;     // 0/1 -> rows rh*16..rh*16+15
    float acc[16];
    const float bias = fcb[c];
    #pragma unroll
    for (int r = 0; r < 16; ++r) acc[r] = bias;

    for (int hh = 0; hh < HH; ++hh) {
        float w = fcWT[hh * CC + c];
        #pragma unroll
        for (int r = 0; r < 16; ++r)
            acc[r] = fmaf(ytile[rh * 16 + r][hh], w, acc[r]);
    }
    #pragma unroll
    for (int r = 0; r < 16; ++r) {
        int b = b0 + rh * 16 + r;
        out[(size_t)b * (TT * CC) + t * CC + c] = acc[r];
    }
}

extern "C" void kernel_launch(void* const* d_in, const int* in_sizes, int n_in,
                              void* d_out, int out_size, void* d_ws, size_t ws_size,
                              hipStream_t stream)
{
    const float* x    = (const float*)d_in[0];
    const float* Wih1 = (const float*)d_in[1];
    const float* Whh1 = (const float*)d_in[2];
    const float* bih1 = (const float*)d_in[3];
    const float* bhh1 = (const float*)d_in[4];
    const float* Wih2 = (const float*)d_in[5];
    const float* Whh2 = (const float*)d_in[6];
    const float* bih2 = (const float*)d_in[7];
    const float* bhh2 = (const float*)d_in[8];
    const float* w_t  = (const float*)d_in[9];
    const float* fcW  = (const float*)d_in[10];
    const float* fcb  = (const float*)d_in[11];
    float* out = (float*)d_out;

    float* ws   = (float*)d_ws;
    float* WT1  = ws + OFF_WT1;
    float* WTi2 = ws + OFF_WTI2;
    float* WTh2 = ws + OFF_WTH2;
    float* fcWT = ws + OFF_FCWT;
    float* b1   = ws + OFF_B1;
    float* b2   = ws + OFF_B2;
    float* h2a  = ws + OFF_H2A;
    float* dold = ws + OFF_DOLD;
    float* dh   = ws + OFF_DH;
    float* mt   = ws + OFF_MT;
    float* st   = ws + OFF_ST;

    k0_prep<<<dim3((G4 * HH + 255) / 256), dim3(256), 0, stream>>>(
        Whh1, Wih2, Whh2, fcW, bih1, bhh1, bih2, bhh2,
        WT1, WTi2, WTh2, fcWT, b1, b2);

    k1_lstm<<<dim3(BB / NB), dim3(512), 0, stream>>>(
        x, Wih1, WT1, WTi2, WTh2, b1, b2, h2a);

    k2_dots<<<dim3(256), dim3(256), 0, stream>>>(h2a, w_t, dold, dh);

    k3_stats<<<dim3(TT), dim3(256), 0, stream>>>(dold, dh, mt, st);

    k4_attn<<<dim3(BB), dim3(128), 0, stream>>>(h2a, dold, dh, mt, st);

    k5_fc<<<dim3(TT, BB / 32), dim3(256), 0, stream>>>(h2a, fcWT, fcb, out);
}